// Round 10
// baseline (339.492 us; speedup 1.0000x reference)
//
#include <hip/hip_runtime.h>

using short8 = __attribute__((ext_vector_type(8))) short;
using u32x4  = __attribute__((ext_vector_type(4))) unsigned;
using u32x2  = __attribute__((ext_vector_type(2))) unsigned;
using f32x4  = __attribute__((ext_vector_type(4))) float;

#define LB 136                      // bf16 row stride (shorts) = 272 B
#define TILE_SH (64*LB)             // one tile buffer = 8704 shorts = 17408 B
#define SMEM_BYTES (4*TILE_SH*2 + 896*4)   // 69632 + 3584 = 73216 B -> 2 blocks/CU

#define PK_CW1 0
#define PK_CW2 16384
#define PK_DW1 32768
#define PK_DW2 49152
#define PK_FW1 65536
#define PK_FW2 98304
#define BF_OFF 262144               // byte offset of folded biases in ws

__device__ __forceinline__ short f2bf(float f) {
  __bf16 h = (__bf16)f;
  return __builtin_bit_cast(short, h);
}
__device__ __forceinline__ float bf2f(short s) {
  unsigned u = ((unsigned)(unsigned short)s) << 16;
  return __builtin_bit_cast(float, u);
}
__device__ __forceinline__ unsigned pkbf(float lo, float hi) {
  return ((unsigned)(unsigned short)f2bf(hi) << 16) | (unsigned)(unsigned short)f2bf(lo);
}
__device__ __forceinline__ float bfLo(unsigned u) {
  return __builtin_bit_cast(float, u << 16);
}
__device__ __forceinline__ float bfHi(unsigned u) {
  return __builtin_bit_cast(float, u & 0xffff0000u);
}

__device__ __forceinline__ float gelu_f(float x) {
  float x2 = x * x;
  float u2 = x * fmaf(x2, 0.1029442495f, 2.3021181583f);
  float e  = __builtin_amdgcn_exp2f(u2);
  float r  = __builtin_amdgcn_rcpf(1.0f + e);
  return fmaf(-x, r, x);
}

__device__ __forceinline__ f32x4 mfma16(short8 a, short8 b, f32x4 c) {
  return __builtin_amdgcn_mfma_f32_16x16x32_bf16(a, b, c, 0, 0, 0);
}

// gelu+bias, pack to bf16, cross-lane assemble into a layer-2 B-fragment.
__device__ __forceinline__ short8 asm_frag(f32x4 F0, f32x4 F1, float4 ba, float4 bb,
                                           int src0, int src1, bool lo2) {
  unsigned Ta0 = pkbf(gelu_f(F0[0] + ba.x), gelu_f(F0[1] + ba.y));
  unsigned Tb0 = pkbf(gelu_f(F0[2] + ba.z), gelu_f(F0[3] + ba.w));
  unsigned Ta1 = pkbf(gelu_f(F1[0] + bb.x), gelu_f(F1[1] + bb.y));
  unsigned Tb1 = pkbf(gelu_f(F1[2] + bb.z), gelu_f(F1[3] + bb.w));
  unsigned A1 = (unsigned)__shfl((int)Ta0, src0);
  unsigned A2 = (unsigned)__shfl((int)Ta1, src0);
  unsigned B1 = (unsigned)__shfl((int)Tb0, src0);
  unsigned B2 = (unsigned)__shfl((int)Tb1, src0);
  unsigned C1 = (unsigned)__shfl((int)Ta0, src1);
  unsigned C2 = (unsigned)__shfl((int)Ta1, src1);
  unsigned D1 = (unsigned)__shfl((int)Tb0, src1);
  unsigned D2 = (unsigned)__shfl((int)Tb1, src1);
  u32x4 dwf;
  dwf[0] = lo2 ? A1 : A2;
  dwf[1] = lo2 ? B1 : B2;
  dwf[2] = lo2 ? C1 : C2;
  dwf[3] = lo2 ? D1 : D2;
  return __builtin_bit_cast(short8, dwf);
}

// Fragment-major bf16 prepack; W1-type rows scaled by ln_g (g-folding).
__global__ void pack_weights_k(const float* __restrict__ cW1, const float* __restrict__ cW2,
                               const float* __restrict__ dW1, const float* __restrict__ dW2,
                               const float* __restrict__ fW1, const float* __restrict__ fW2,
                               const float* __restrict__ g, short* __restrict__ pk) {
  int fid  = blockIdx.x * 256 + threadIdx.x;
  int lane = fid & 63;
  int fbg  = fid >> 6;
  const float* W; int N; int fb; bool sc;
  if (fbg < 32)       { W = cW1; N = 128; fb = fbg;       sc = true;  }
  else if (fbg < 64)  { W = cW2; N = 128; fb = fbg - 32;  sc = false; }
  else if (fbg < 96)  { W = dW1; N = 128; fb = fbg - 64;  sc = true;  }
  else if (fbg < 128) { W = dW2; N = 128; fb = fbg - 96;  sc = false; }
  else if (fbg < 192) { W = fW1; N = 256; fb = fbg - 128; sc = true;  }
  else                { W = fW2; N = 128; fb = fbg - 192; sc = false; }
  int nt = fb % (N >> 4);
  int kk = fb / (N >> 4);
  int row0 = kk * 32 + (lane >> 4) * 8;
  int col  = nt * 16 + (lane & 15);
  short8 v;
  #pragma unroll
  for (int j = 0; j < 8; ++j) {
    float s = sc ? g[row0 + j] : 1.0f;
    v[j] = f2bf(W[(row0 + j) * N + col] * s);
  }
  *(short8*)&pk[fbg * 512 + lane * 8] = v;
}

// Folded layer-1 biases: bf[0:128)=ln_b@cW1+c_b1, [128:256)=d_b1, [256:512)=ln_b@fW1+f_b1
__global__ void bias_fold_k(const float* __restrict__ lnb,
                            const float* __restrict__ cW1, const float* __restrict__ cb1,
                            const float* __restrict__ db1,
                            const float* __restrict__ fW1, const float* __restrict__ fb1,
                            float* __restrict__ bo) {
  int tid = blockIdx.x * 256 + threadIdx.x;
  if (tid < 128) {
    float s = cb1[tid];
    for (int k = 0; k < 128; ++k) s = fmaf(lnb[k], cW1[k * 128 + tid], s);
    bo[tid] = s;
  } else if (tid < 256) {
    bo[tid] = db1[tid - 128];
  } else if (tid < 512) {
    int n = tid - 256;
    float s = fb1[n];
    for (int k = 0; k < 128; ++k) s = fmaf(lnb[k], fW1[k * 256 + n], s);
    bo[256 + n] = s;
  }
}

// Phase A: load x, row-LN stats, pair-combine via shfl_xor(16) -> P1x; x -> XPv.
#define PHASE_A(i, XPv, XG, P1x)                                                 \
  {                                                                              \
    int row = 4 * w + h + 16 * (i);                                              \
    float4 a = XG[row * 32 + 2 * c];                                             \
    float4 b = XG[row * 32 + 2 * c + 1];                                         \
    float v0 = a.x, v1 = a.y, v2 = a.z, v3 = a.w;                                \
    float v4 = b.x, v5 = b.y, v6 = b.z, v7 = b.w;                                \
    float s = v0 + v1 + v2 + v3 + v4 + v5 + v6 + v7;                             \
    float q = v0 * v0; q = fmaf(v1, v1, q); q = fmaf(v2, v2, q);                 \
    q = fmaf(v3, v3, q); q = fmaf(v4, v4, q); q = fmaf(v5, v5, q);               \
    q = fmaf(v6, v6, q); q = fmaf(v7, v7, q);                                    \
    s += __shfl_xor(s, 1); q += __shfl_xor(q, 1);                                \
    s += __shfl_xor(s, 2); q += __shfl_xor(q, 2);                                \
    s += __shfl_xor(s, 4); q += __shfl_xor(q, 4);                                \
    s += __shfl_xor(s, 8); q += __shfl_xor(q, 8);                                \
    float mu = s * (1.0f / 128.0f);                                              \
    float rs = rsqrtf(q * (1.0f / 128.0f) - mu * mu + 1e-5f);                    \
    float nb = -mu * rs;                                                         \
    int jrow = 2 * w + (h >> 1) + 8 * (i) + 32 * (h & 1);                        \
    u32x4 nv;                                                                    \
    float n0 = fmaf(v0, rs, nb), n1 = fmaf(v1, rs, nb);                          \
    float o0 = __shfl_xor(n0, 16), o1 = __shfl_xor(n1, 16);                      \
    nv[0] = pkbf(fmaf(sfac, n0, 0.5f * o0), fmaf(sfac, n1, 0.5f * o1));          \
    n0 = fmaf(v2, rs, nb); n1 = fmaf(v3, rs, nb);                                \
    o0 = __shfl_xor(n0, 16); o1 = __shfl_xor(n1, 16);                            \
    nv[1] = pkbf(fmaf(sfac, n0, 0.5f * o0), fmaf(sfac, n1, 0.5f * o1));          \
    n0 = fmaf(v4, rs, nb); n1 = fmaf(v5, rs, nb);                                \
    o0 = __shfl_xor(n0, 16); o1 = __shfl_xor(n1, 16);                            \
    nv[2] = pkbf(fmaf(sfac, n0, 0.5f * o0), fmaf(sfac, n1, 0.5f * o1));          \
    n0 = fmaf(v6, rs, nb); n1 = fmaf(v7, rs, nb);                                \
    o0 = __shfl_xor(n0, 16); o1 = __shfl_xor(n1, 16);                            \
    nv[3] = pkbf(fmaf(sfac, n0, 0.5f * o0), fmaf(sfac, n1, 0.5f * o1));          \
    *(short8*)&P1x[jrow * LB + 8 * c] = __builtin_bit_cast(short8, nv);          \
    XPv[0] = pkbf(v0, v1); XPv[1] = pkbf(v2, v3);                                \
    XPv[2] = pkbf(v4, v5); XPv[3] = pkbf(v6, v7);                                \
  }

// Phase R+D: out = x + uc +- ud; LN(out); frag row -> P1x; XPv := out
#define PHASE_R(i, XPv, P1x, P2x)                                                \
  {                                                                              \
    int j = 2 * w + (h >> 1) + 8 * (i);                                          \
    short8 uc8 = *(const short8*)&P2x[j * LB + 8 * c];                           \
    short8 ud8 = *(const short8*)&P2x[(32 + j) * LB + 8 * c];                    \
    float o0 = fmaf(sfac2, bf2f(ud8[0]), bfLo(XPv[0]) + bf2f(uc8[0]));           \
    float o1 = fmaf(sfac2, bf2f(ud8[1]), bfHi(XPv[0]) + bf2f(uc8[1]));           \
    float o2 = fmaf(sfac2, bf2f(ud8[2]), bfLo(XPv[1]) + bf2f(uc8[2]));           \
    float o3 = fmaf(sfac2, bf2f(ud8[3]), bfHi(XPv[1]) + bf2f(uc8[3]));           \
    float o4 = fmaf(sfac2, bf2f(ud8[4]), bfLo(XPv[2]) + bf2f(uc8[4]));           \
    float o5 = fmaf(sfac2, bf2f(ud8[5]), bfHi(XPv[2]) + bf2f(uc8[5]));           \
    float o6 = fmaf(sfac2, bf2f(ud8[6]), bfLo(XPv[3]) + bf2f(uc8[6]));           \
    float o7 = fmaf(sfac2, bf2f(ud8[7]), bfHi(XPv[3]) + bf2f(uc8[7]));           \
    float s = o0 + o1 + o2 + o3 + o4 + o5 + o6 + o7;                             \
    float q = o0 * o0; q = fmaf(o1, o1, q); q = fmaf(o2, o2, q);                 \
    q = fmaf(o3, o3, q); q = fmaf(o4, o4, q); q = fmaf(o5, o5, q);               \
    q = fmaf(o6, o6, q); q = fmaf(o7, o7, q);                                    \
    s += __shfl_xor(s, 1); q += __shfl_xor(q, 1);                                \
    s += __shfl_xor(s, 2); q += __shfl_xor(q, 2);                                \
    s += __shfl_xor(s, 4); q += __shfl_xor(q, 4);                                \
    s += __shfl_xor(s, 8); q += __shfl_xor(q, 8);                                \
    float mu = s * (1.0f / 128.0f);                                              \
    float rs = rsqrtf(q * (1.0f / 128.0f) - mu * mu + 1e-5f);                    \
    float nb = -mu * rs;                                                         \
    int row = 4 * w + h + 16 * (i);                                              \
    u32x4 nv;                                                                    \
    nv[0] = pkbf(fmaf(o0, rs, nb), fmaf(o1, rs, nb));                            \
    nv[1] = pkbf(fmaf(o2, rs, nb), fmaf(o3, rs, nb));                            \
    nv[2] = pkbf(fmaf(o4, rs, nb), fmaf(o5, rs, nb));                            \
    nv[3] = pkbf(fmaf(o6, rs, nb), fmaf(o7, rs, nb));                            \
    *(short8*)&P1x[row * LB + 8 * c] = __builtin_bit_cast(short8, nv);           \
    XPv[0] = pkbf(o0, o1); XPv[1] = pkbf(o2, o3);                                \
    XPv[2] = pkbf(o4, o5); XPv[3] = pkbf(o6, o7);                                \
  }

// Final: out = out_reg + upd, coalesced float4 store
#define STORE_F(i, XPv, OG, P2x)                                                 \
  {                                                                              \
    int row = 4 * w + h + 16 * (i);                                              \
    short8 u8 = *(const short8*)&P2x[row * LB + 8 * c];                          \
    float4 a, b;                                                                 \
    a.x = bfLo(XPv[0]) + bf2f(u8[0]); a.y = bfHi(XPv[0]) + bf2f(u8[1]);          \
    a.z = bfLo(XPv[1]) + bf2f(u8[2]); a.w = bfHi(XPv[1]) + bf2f(u8[3]);          \
    b.x = bfLo(XPv[2]) + bf2f(u8[4]); b.y = bfHi(XPv[2]) + bf2f(u8[5]);          \
    b.z = bfLo(XPv[3]) + bf2f(u8[6]); b.w = bfHi(XPv[3]) + bf2f(u8[7]);          \
    OG[row * 32 + 2 * c]     = a;                                                \
    OG[row * 32 + 2 * c + 1] = b;                                                \
  }

__global__ __launch_bounds__(256, 2)
void hemi_fused_k(const float* __restrict__ x, const short* __restrict__ pk,
                  const float* __restrict__ bf1,
                  const float* __restrict__ c_b2, const float* __restrict__ d_b2,
                  const float* __restrict__ f_b2,
                  float* __restrict__ out) {
  extern __shared__ short smem[];
  short* P1a = smem;                 // tile0 frag buffer
  short* P2a = smem + TILE_SH;       // tile0 uc/ud, later upd
  short* P1b = smem + 2 * TILE_SH;   // tile1 frag buffer
  short* P2b = smem + 3 * TILE_SH;   // tile1 uc/ud, later upd
  float* sbias = (float*)(smem + 4 * TILE_SH);   // 896 floats

  const int t = threadIdx.x;
  const int w = t >> 6, l = t & 63;
  const int h = l >> 4, c = l & 15;
  const size_t base = (size_t)blockIdx.x * 16384;   // two 64x128 tiles

  // stage biases into LDS (fenced by sync1)
  #pragma unroll
  for (int i = t; i < 512; i += 256) sbias[i] = bf1[i];
  if (t < 128) {
    sbias[512 + t] = c_b2[t];
    sbias[640 + t] = d_b2[t];
    sbias[768 + t] = f_b2[t];
  }

  const float4* xga = (const float4*)(x + base);
  const float4* xgb = (const float4*)(x + base + 8192);
  const float sfac  = (h & 1) ? -0.5f : 0.5f;
  const float sfac2 = (h & 1) ? -1.0f : 1.0f;

  u32x4 xp0, xp1, xp2, xp3;   // tile0 x (later out), packed bf16 pairs
  u32x4 yp0, yp1, yp2, yp3;   // tile1

  PHASE_A(0, xp0, xga, P1a)
  PHASE_A(1, xp1, xga, P1a)
  PHASE_A(2, xp2, xga, P1a)
  PHASE_A(3, xp3, xga, P1a)
  PHASE_A(0, yp0, xgb, P1b)
  PHASE_A(1, yp1, xgb, P1b)
  PHASE_A(2, yp2, xgb, P1b)
  PHASE_A(3, yp3, xgb, P1b)
  __syncthreads();   // sync1: cmn/dif + biases ready

  const int src0 = c + 32 * (h & 1);
  const int src1 = src0 + 16;
  const bool lo2 = (h < 2);
  const f32x4 Z = {0.f, 0.f, 0.f, 0.f};

  // ---------------- Phase C: pair-MLP, 2 tiles share every weight load
  {
    const short* W1    = pk + ((w < 2) ? PK_CW1 : PK_DW1) + l * 8;
    const short* W2    = pk + ((w < 2) ? PK_CW2 : PK_DW2) + l * 8;
    const float* bias1 = sbias + ((w < 2) ? 0 : 128);
    const float* bias2 = sbias + ((w < 2) ? 512 : 640);
    const int arow = 16 * (w & 1) + 32 * (w >> 1);
    short8 sa0 = *(const short8*)&P1a[(arow + c) * LB +  0 + 8 * h];
    short8 sa1 = *(const short8*)&P1a[(arow + c) * LB + 32 + 8 * h];
    short8 sa2 = *(const short8*)&P1a[(arow + c) * LB + 64 + 8 * h];
    short8 sa3 = *(const short8*)&P1a[(arow + c) * LB + 96 + 8 * h];
    short8 sb0 = *(const short8*)&P1b[(arow + c) * LB +  0 + 8 * h];
    short8 sb1 = *(const short8*)&P1b[(arow + c) * LB + 32 + 8 * h];
    short8 sb2 = *(const short8*)&P1b[(arow + c) * LB + 64 + 8 * h];
    short8 sb3 = *(const short8*)&P1b[(arow + c) * LB + 96 + 8 * h];
    f32x4 A0 = Z, A1 = Z, A2 = Z, A3 = Z, A4 = Z, A5 = Z, A6 = Z, A7 = Z;
    f32x4 B0 = Z, B1 = Z, B2 = Z, B3 = Z, B4 = Z, B5 = Z, B6 = Z, B7 = Z;
#define C_SLICE(u)                                                            \
    {                                                                         \
      const short8 wa0 = *(const short8*)&W1[(0 * 8 + 2 * (u)) * 512];        \
      const short8 wa1 = *(const short8*)&W1[(1 * 8 + 2 * (u)) * 512];        \
      const short8 wa2 = *(const short8*)&W1[(2 * 8 + 2 * (u)) * 512];        \
      const short8 wa3 = *(const short8*)&W1[(3 * 8 + 2 * (u)) * 512];        \
      const short8 wb0 = *(const short8*)&W1[(0 * 8 + 2 * (u) + 1) * 512];    \
      const short8 wb1 = *(const short8*)&W1[(1 * 8 + 2 * (u) + 1) * 512];    \
      const short8 wb2 = *(const short8*)&W1[(2 * 8 + 2 * (u) + 1) * 512];    \
      const short8 wb3 = *(const short8*)&W1[(3 * 8 + 2 * (u) + 1) * 512];    \
      f32x4 F0a = Z, F1a = Z, F0b = Z, F1b = Z;                               \
      F0a = mfma16(wa0, sa0, F0a); F0b = mfma16(wa0, sb0, F0b);               \
      F0a = mfma16(wa1, sa1, F0a); F0b = mfma16(wa1, sb1, F0b);               \
      F0a = mfma16(wa2, sa2, F0a); F0b = mfma16(wa2, sb2, F0b);               \
      F0a = mfma16(wa3, sa3, F0a); F0b = mfma16(wa3, sb3, F0b);               \
      F1a = mfma16(wb0, sa0, F1a); F1b = mfma16(wb0, sb0, F1b);               \
      F1a = mfma16(wb1, sa1, F1a); F1b = mfma16(wb1, sb1, F1b);               \
      F1a = mfma16(wb2, sa2, F1a); F1b = mfma16(wb2, sb2, F1b);               \
      F1a = mfma16(wb3, sa3, F1a); F1b = mfma16(wb3, sb3, F1b);               \
      float4 ba = *(const float4*)&bias1[16 * (2 * (u)) + 4 * h];             \
      float4 bb = *(const float4*)&bias1[16 * (2 * (u) + 1) + 4 * h];         \
      short8 Ga = asm_frag(F0a, F1a, ba, bb, src0, src1, lo2);                \
      short8 Gb = asm_frag(F0b, F1b, ba, bb, src0, src1, lo2);                \
      const short8 v0 = *(const short8*)&W2[((u) * 8 + 0) * 512];             \
      const short8 v1 = *(const short8*)&W2[((u) * 8 + 1) * 512];             \
      const short8 v2 = *(const short8*)&W2[((u) * 8 + 2) * 512];             \
      const short8 v3 = *(const short8*)&W2[((u) * 8 + 3) * 512];             \
      const short8 v4 = *(const short8*)&W2[((u) * 8 + 4) * 512];             \
      const short8 v5 = *(const short8*)&W2[((u) * 8 + 5) * 512];             \
      const short8 v6 = *(const short8*)&W2[((u) * 8 + 6) * 512];             \
      const short8 v7 = *(const short8*)&W2[((u) * 8 + 7) * 512];             \
      A0 = mfma16(v0, Ga, A0); B0 = mfma16(v0, Gb, B0);                       \
      A1 = mfma16(v1, Ga, A1); B1 = mfma16(v1, Gb, B1);                       \
      A2 = mfma16(v2, Ga, A2); B2 = mfma16(v2, Gb, B2);                       \
      A3 = mfma16(v3, Ga, A3); B3 = mfma16(v3, Gb, B3);                       \
      A4 = mfma16(v4, Ga, A4); B4 = mfma16(v4, Gb, B4);                       \
      A5 = mfma16(v5, Ga, A5); B5 = mfma16(v5, Gb, B5);                       \
      A6 = mfma16(v6, Ga, A6); B6 = mfma16(v6, Gb, B6);                       \
      A7 = mfma16(v7, Ga, A7); B7 = mfma16(v7, Gb, B7);                       \
    }
    C_SLICE(0)
    C_SLICE(1)
    C_SLICE(2)
    C_SLICE(3)
#undef C_SLICE
#define C_EPI(t2, A, B)                                                       \
    {                                                                         \
      float4 b4 = *(const float4*)&bias2[16 * (t2) + 4 * h];                  \
      u32x2 dd;                                                               \
      dd[0] = pkbf(A[0] + b4.x, A[1] + b4.y);                                 \
      dd[1] = pkbf(A[2] + b4.z, A[3] + b4.w);                                 \
      *(u32x2*)&P2a[(arow + c) * LB + 16 * (t2) + 4 * h] = dd;                \
      dd[0] = pkbf(B[0] + b4.x, B[1] + b4.y);                                 \
      dd[1] = pkbf(B[2] + b4.z, B[3] + b4.w);                                 \
      *(u32x2*)&P2b[(arow + c) * LB + 16 * (t2) + 4 * h] = dd;                \
    }
    C_EPI(0, A0, B0) C_EPI(1, A1, B1) C_EPI(2, A2, B2) C_EPI(3, A3, B3)
    C_EPI(4, A4, B4) C_EPI(5, A5, B5) C_EPI(6, A6, B6) C_EPI(7, A7, B7)
#undef C_EPI
  }
  __syncthreads();   // sync2: uc/ud complete

  PHASE_R(0, xp0, P1a, P2a)
  PHASE_R(1, xp1, P1a, P2a)
  PHASE_R(2, xp2, P1a, P2a)
  PHASE_R(3, xp3, P1a, P2a)
  PHASE_R(0, yp0, P1b, P2b)
  PHASE_R(1, yp1, P1b, P2b)
  PHASE_R(2, yp2, P1b, P2b)
  PHASE_R(3, yp3, P1b, P2b)
  __syncthreads();   // sync3: n_out complete

  // ---------------- Phase E: f-MLP 128->256->128, 2 tiles share weight loads
  {
    const short* W1    = pk + PK_FW1 + l * 8;
    const short* W2    = pk + PK_FW2 + l * 8;
    const float* biasF = sbias + 256;
    const int nrow = (16 * w + c) * LB + 8 * h;
    short8 na0 = *(const short8*)&P1a[nrow +  0];
    short8 na1 = *(const short8*)&P1a[nrow + 32];
    short8 na2 = *(const short8*)&P1a[nrow + 64];
    short8 na3 = *(const short8*)&P1a[nrow + 96];
    short8 nb0 = *(const short8*)&P1b[nrow +  0];
    short8 nb1 = *(const short8*)&P1b[nrow + 32];
    short8 nb2 = *(const short8*)&P1b[nrow + 64];
    short8 nb3 = *(const short8*)&P1b[nrow + 96];
    f32x4 A0 = Z, A1 = Z, A2 = Z, A3 = Z, A4 = Z, A5 = Z, A6 = Z, A7 = Z;
    f32x4 B0 = Z, B1 = Z, B2 = Z, B3 = Z, B4 = Z, B5 = Z, B6 = Z, B7 = Z;
#define E_SLICE(u)                                                            \
    {                                                                         \
      const short8 wa0 = *(const short8*)&W1[(0 * 16 + 2 * (u)) * 512];       \
      const short8 wa1 = *(const short8*)&W1[(1 * 16 + 2 * (u)) * 512];       \
      const short8 wa2 = *(const short8*)&W1[(2 * 16 + 2 * (u)) * 512];       \
      const short8 wa3 = *(const short8*)&W1[(3 * 16 + 2 * (u)) * 512];       \
      const short8 wb0 = *(const short8*)&W1[(0 * 16 + 2 * (u) + 1) * 512];   \
      const short8 wb1 = *(const short8*)&W1[(1 * 16 + 2 * (u) + 1) * 512];   \
      const short8 wb2 = *(const short8*)&W1[(2 * 16 + 2 * (u) + 1) * 512];   \
      const short8 wb3 = *(const short8*)&W1[(3 * 16 + 2 * (u) + 1) * 512];   \
      f32x4 F0a = Z, F1a = Z, F0b = Z, F1b = Z;                               \
      F0a = mfma16(wa0, na0, F0a); F0b = mfma16(wa0, nb0, F0b);               \
      F0a = mfma16(wa1, na1, F0a); F0b = mfma16(wa1, nb1, F0b);               \
      F0a = mfma16(wa2, na2, F0a); F0b = mfma16(wa2, nb2, F0b);               \
      F0a = mfma16(wa3, na3, F0a); F0b = mfma16(wa3, nb3, F0b);               \
      F1a = mfma16(wb0, na0, F1a); F1b = mfma16(wb0, nb0, F1b);               \
      F1a = mfma16(wb1, na1, F1a); F1b = mfma16(wb1, nb1, F1b);               \
      F1a = mfma16(wb2, na2, F1a); F1b = mfma16(wb2, nb2, F1b);               \
      F1a = mfma16(wb3, na3, F1a); F1b = mfma16(wb3, nb3, F1b);               \
      float4 ba = *(const float4*)&biasF[16 * (2 * (u)) + 4 * h];             \
      float4 bb = *(const float4*)&biasF[16 * (2 * (u) + 1) + 4 * h];         \
      short8 Ga = asm_frag(F0a, F1a, ba, bb, src0, src1, lo2);                \
      short8 Gb = asm_frag(F0b, F1b, ba, bb, src0, src1, lo2);                \
      const short8 v0 = *(const short8*)&W2[((u) * 8 + 0) * 512];             \
      const short8 v1 = *(const short8*)&W2[((u) * 8 + 1) * 512];             \
      const short8 v2 = *(const short8*)&W2[((u) * 8 + 2) * 512];             \
      const short8 v3 = *(const short8*)&W2[((u) * 8 + 3) * 512];             \
      const short8 v4 = *(const short8*)&W2[((u) * 8 + 4) * 512];             \
      const short8 v5 = *(const short8*)&W2[((u) * 8 + 5) * 512];             \
      const short8 v6 = *(const short8*)&W2[((u) * 8 + 6) * 512];             \
      const short8 v7 = *(const short8*)&W2[((u) * 8 + 7) * 512];             \
      A0 = mfma16(v0, Ga, A0); B0 = mfma16(v0, Gb, B0);                       \
      A1 = mfma16(v1, Ga, A1); B1 = mfma16(v1, Gb, B1);                       \
      A2 = mfma16(v2, Ga, A2); B2 = mfma16(v2, Gb, B2);                       \
      A3 = mfma16(v3, Ga, A3); B3 = mfma16(v3, Gb, B3);                       \
      A4 = mfma16(v4, Ga, A4); B4 = mfma16(v4, Gb, B4);                       \
      A5 = mfma16(v5, Ga, A5); B5 = mfma16(v5, Gb, B5);                       \
      A6 = mfma16(v6, Ga, A6); B6 = mfma16(v6, Gb, B6);                       \
      A7 = mfma16(v7, Ga, A7); B7 = mfma16(v7, Gb, B7);                       \
    }
    E_SLICE(0)
    E_SLICE(1)
    E_SLICE(2)
    E_SLICE(3)
    E_SLICE(4)
    E_SLICE(5)
    E_SLICE(6)
    E_SLICE(7)
#undef E_SLICE
#define E_EPI(t2, A, B)                                                       \
    {                                                                         \
      float4 b4 = *(const float4*)&sbias[768 + 16 * (t2) + 4 * h];            \
      u32x2 dd;                                                               \
      dd[0] = pkbf(A[0] + b4.x, A[1] + b4.y);                                 \
      dd[1] = pkbf(A[2] + b4.z, A[3] + b4.w);                                 \
      *(u32x2*)&P2a[(16 * w + c) * LB + 16 * (t2) + 4 * h] = dd;              \
      dd[0] = pkbf(B[0] + b4.x, B[1] + b4.y);                                 \
      dd[1] = pkbf(B[2] + b4.z, B[3] + b4.w);                                 \
      *(u32x2*)&P2b[(16 * w + c) * LB + 16 * (t2) + 4 * h] = dd;              \
    }
    E_EPI(0, A0, B0) E_EPI(1, A1, B1) E_EPI(2, A2, B2) E_EPI(3, A3, B3)
    E_EPI(4, A4, B4) E_EPI(5, A5, B5) E_EPI(6, A6, B6) E_EPI(7, A7, B7)
#undef E_EPI
  }
  __syncthreads();   // sync4: upd complete

  float4* oga = (float4*)(out + base);
  float4* ogb = (float4*)(out + base + 8192);
  STORE_F(0, xp0, oga, P2a)
  STORE_F(1, xp1, oga, P2a)
  STORE_F(2, xp2, oga, P2a)
  STORE_F(3, xp3, oga, P2a)
  STORE_F(0, yp0, ogb, P2b)
  STORE_F(1, yp1, ogb, P2b)
  STORE_F(2, yp2, ogb, P2b)
  STORE_F(3, yp3, ogb, P2b)
}

extern "C" void kernel_launch(void* const* d_in, const int* in_sizes, int n_in,
                              void* d_out, int out_size, void* d_ws, size_t ws_size,
                              hipStream_t stream) {
  (void)in_sizes; (void)n_in; (void)out_size; (void)ws_size;
  const float* x    = (const float*)d_in[0];
  const float* ln_g = (const float*)d_in[1];
  const float* ln_b = (const float*)d_in[2];
  const float* cW1  = (const float*)d_in[3];
  const float* c_b1 = (const float*)d_in[4];
  const float* cW2  = (const float*)d_in[5];
  const float* c_b2 = (const float*)d_in[6];
  const float* dW1  = (const float*)d_in[7];
  const float* d_b1 = (const float*)d_in[8];
  const float* dW2  = (const float*)d_in[9];
  const float* d_b2 = (const float*)d_in[10];
  const float* fW1  = (const float*)d_in[11];
  const float* f_b1 = (const float*)d_in[12];
  const float* fW2  = (const float*)d_in[13];
  const float* f_b2 = (const float*)d_in[14];
  short* pk   = (short*)d_ws;                         // 256 KB fragments
  float* bfv  = (float*)((char*)d_ws + BF_OFF);       // 512 folded-bias floats
  float* out  = (float*)d_out;

  hipFuncSetAttribute((const void*)hemi_fused_k,
                      hipFuncAttributeMaxDynamicSharedMemorySize, SMEM_BYTES);

  pack_weights_k<<<64, 256, 0, stream>>>(cW1, cW2, dW1, dW2, fW1, fW2, ln_g, pk);
  bias_fold_k<<<2, 256, 0, stream>>>(ln_b, cW1, c_b1, d_b1, fW1, f_b1, bfv);
  hemi_fused_k<<<4096, 256, SMEM_BYTES, stream>>>(x, pk, bfv, c_b2, d_b2, f_b2, out);
}